// Round 1
// baseline (246.532 us; speedup 1.0000x reference)
//
#include <hip/hip_runtime.h>

// CRF sequence labeling: B=64, S=512, H=1024, L=9
// Pipeline:
//   K1 logits_kernel : feats[b][s][l] = (inputs[b,s,:]·W[l,:] + bias[l]) * log2(e)
//   K2 chunk_kernel  : per (b, chunk of 32 steps, row i): 9x9 log2-semiring
//                      chunk transfer-matrix row via vector recursion
//   K3 final_kernel  : per batch: alpha0 ⊗ P_0 ⊗ ... ⊗ P_15, + gold path score
//   K4 mean_kernel   : mean over batches * ln(2)
// All log-sum-exp math is done in base-2 domain (inputs pre-scaled by log2 e)
// so LSE = max + log2(sum 2^x) uses raw v_exp_f32/v_log_f32.

#define BATCH 64
#define SEQ   512
#define HID   1024
#define NLAB  9
#define CHUNK 32
#define NCHUNK (SEQ / CHUNK)   // 16
#define NREC (BATCH * NCHUNK * NLAB)  // 9216 row recursions

__device__ __forceinline__ float exp2_fast(float x) { return __builtin_amdgcn_exp2f(x); }
__device__ __forceinline__ float log2_fast(float x) { return __builtin_amdgcn_logf(x); }

#define LOG2E 1.4426950408889634f
#define LN2   0.6931471805599453f

// ---------------------------------------------------------------------------
// K1: logits. Grid: (B*S/8) blocks x 256. Wave handles 2 rows.
// W staged in LDS with +1-per-32-floats skew: phys = col + (col>>5).
// Lane covers 16 contiguous cols; col0 is 16-aligned so (col>>5) is constant
// across the lane's 16 cols -> contiguous LDS reads, 2-way bank alias (free).
// ---------------------------------------------------------------------------
__global__ __launch_bounds__(256) void logits_kernel(
    const float* __restrict__ inp, const float* __restrict__ Wg,
    const float* __restrict__ bias, float* __restrict__ feats)
{
    __shared__ float Wl[NLAB * 1056];   // 1024 + 32 skew pad per label row
    const int tid = threadIdx.x;
    for (int i = tid; i < NLAB * HID; i += 256) {
        int l = i >> 10, col = i & 1023;
        Wl[l * 1056 + col + (col >> 5)] = Wg[i];
    }
    __syncthreads();

    const int lane = tid & 63;
    const int wv = tid >> 6;
    const long row0 = (long)blockIdx.x * 8 + wv * 2;
    const int col0 = lane * 16;
    const int sk = col0 + (col0 >> 5);

    float xs0[16], xs1[16];
    {
        const float* r0 = inp + row0 * HID + col0;
        const float* r1 = r0 + HID;
        #pragma unroll
        for (int q = 0; q < 4; ++q) {
            ((float4*)xs0)[q] = ((const float4*)r0)[q];
            ((float4*)xs1)[q] = ((const float4*)r1)[q];
        }
    }

    float acc0[NLAB], acc1[NLAB];
    #pragma unroll
    for (int l = 0; l < NLAB; ++l) {
        const float* w = &Wl[l * 1056 + sk];
        float a0 = 0.f, a1 = 0.f;
        #pragma unroll
        for (int k = 0; k < 16; ++k) {
            float wk = w[k];
            a0 = fmaf(xs0[k], wk, a0);
            a1 = fmaf(xs1[k], wk, a1);
        }
        acc0[l] = a0; acc1[l] = a1;
    }
    #pragma unroll
    for (int l = 0; l < NLAB; ++l) {
        float a0 = acc0[l], a1 = acc1[l];
        #pragma unroll
        for (int off = 32; off > 0; off >>= 1) {
            a0 += __shfl_xor(a0, off, 64);
            a1 += __shfl_xor(a1, off, 64);
        }
        acc0[l] = a0; acc1[l] = a1;
    }
    if (lane == 0) {
        float* o = feats + row0 * NLAB;
        #pragma unroll
        for (int l = 0; l < NLAB; ++l) {
            float bl = bias[l];
            o[l]        = (acc0[l] + bl) * LOG2E;
            o[NLAB + l] = (acc1[l] + bl) * LOG2E;
        }
    }
}

// ---------------------------------------------------------------------------
// K2: chunk transfer-matrix rows. Each 9-lane group runs one row recursion:
//   row i of P_c = e_i ⊗ M_ts ⊗ ... ⊗ M_{te-1},  M_t[i][j] = trK[i][j]+emitK[t][j]
// Masked steps contribute the identity (0 diag / -1e30 off-diag).
// 7 groups per wave (63 lanes active). Grid: ceil(9216/7) = 1317 blocks x 64.
// ---------------------------------------------------------------------------
__global__ __launch_bounds__(64) void chunk_kernel(
    const float* __restrict__ feats, const float* __restrict__ trans,
    const int* __restrict__ mask, float* __restrict__ P)
{
    const int lane = threadIdx.x;
    const int g = lane / 9;
    const int j = lane - g * 9;
    int rid = blockIdx.x * 7 + g;
    bool act = (g < 7) && (rid < NREC);
    if (!act) rid = 0;

    const int i  = rid % NLAB;
    const int bc = rid / NLAB;
    const int c  = bc & (NCHUNK - 1);
    const int b  = bc >> 4;

    float tr[NLAB];
    #pragma unroll
    for (int k = 0; k < NLAB; ++k) tr[k] = trans[k * NLAB + j] * LOG2E;
    const float tri = trans[i * NLAB + j] * LOG2E;  // direct load, no dyn reg index

    const float* fb = feats + (long)b * SEQ * NLAB;
    const int* mb = mask + b * SEQ;
    const int ts = (c == 0) ? 1 : c * CHUNK;
    const int te = (c + 1) * CHUNK;
    const int sbase = g * 9;

    float a;
    {
        int m0 = mb[ts];
        float e0 = fb[ts * NLAB + j];
        float aid = (i == j) ? 0.0f : -1e30f;
        a = (m0 > 0) ? (tri + e0) : aid;
    }

    float e_nxt = fb[(ts + 1) * NLAB + j];
    int   m_nxt = mb[ts + 1];
    for (int t = ts + 1; t < te; ++t) {
        float e = e_nxt;
        int  mt = m_nxt;
        if (t + 1 < te) {               // prefetch next step's emission/mask
            e_nxt = fb[(t + 1) * NLAB + j];
            m_nxt = mb[t + 1];
        }
        float v[NLAB];
        #pragma unroll
        for (int k = 0; k < NLAB; ++k) v[k] = __shfl(a, sbase + k, 64) + tr[k];
        float m01 = fmaxf(v[0], v[1]), m23 = fmaxf(v[2], v[3]);
        float m45 = fmaxf(v[4], v[5]), m67 = fmaxf(v[6], v[7]);
        float mx = fmaxf(fmaxf(fmaxf(m01, m23), fmaxf(m45, m67)), v[8]);
        float s = 0.0f;
        #pragma unroll
        for (int k = 0; k < NLAB; ++k) s += exp2_fast(v[k] - mx);
        float an = mx + log2_fast(s) + e;
        a = (mt > 0) ? an : a;
    }
    if (act) P[(long)rid * NLAB + j] = a;
}

// ---------------------------------------------------------------------------
// K3: per-batch finalize. Grid: 64 blocks x 64.
//  - gold path score (all 64 lanes, strided over t, then wave-reduce)
//  - alpha = alpha0 ⊗ P_0 ⊗ ... ⊗ P_15 (lanes replicate j = lane%9)
//  - partial[b] = K*(norm - score)
// ---------------------------------------------------------------------------
__global__ __launch_bounds__(64) void final_kernel(
    const float* __restrict__ feats, const float* __restrict__ trans,
    const float* __restrict__ startv, const float* __restrict__ endv,
    const int* __restrict__ labels, const int* __restrict__ mask,
    const float* __restrict__ P, float* __restrict__ partial)
{
    const int b = blockIdx.x, lane = threadIdx.x;
    const float* fb = feats + (long)b * SEQ * NLAB;
    const int* lb = labels + b * SEQ;
    const int* mb = mask + b * SEQ;

    // ---- gold score ----
    float gsum = 0.0f; int msum = 0;
    for (int t = lane; t < SEQ; t += 64) {
        int tag = lb[t];
        int mt = mb[t];
        if (mt > 0) {
            gsum += fb[t * NLAB + tag];            // feats already *K
            msum++;
            if (t > 0) gsum += trans[lb[t - 1] * NLAB + tag] * LOG2E;
        }
    }
    #pragma unroll
    for (int off = 32; off > 0; off >>= 1) {
        gsum += __shfl_xor(gsum, off, 64);
        msum += __shfl_xor(msum, off, 64);
    }

    // ---- alpha chain over chunk matrices ----
    const int j = lane % 9;      // lanes >=9 replicate; shuffles read lanes 0..8
    float al = fb[j] + startv[j] * LOG2E;
    const float* Pb = P + (long)b * NCHUNK * 81;
    float pc[NLAB];
    #pragma unroll
    for (int i = 0; i < NLAB; ++i) pc[i] = Pb[i * NLAB + j];
    #pragma unroll
    for (int c = 0; c < NCHUNK; ++c) {
        float pn[NLAB];
        if (c < NCHUNK - 1) {
            #pragma unroll
            for (int i = 0; i < NLAB; ++i) pn[i] = Pb[(c + 1) * 81 + i * NLAB + j];
        } else {
            #pragma unroll
            for (int i = 0; i < NLAB; ++i) pn[i] = 0.0f;
        }
        float v[NLAB];
        #pragma unroll
        for (int i = 0; i < NLAB; ++i) v[i] = __shfl(al, i, 64) + pc[i];
        float m01 = fmaxf(v[0], v[1]), m23 = fmaxf(v[2], v[3]);
        float m45 = fmaxf(v[4], v[5]), m67 = fmaxf(v[6], v[7]);
        float mx = fmaxf(fmaxf(fmaxf(m01, m23), fmaxf(m45, m67)), v[8]);
        float s = 0.0f;
        #pragma unroll
        for (int i = 0; i < NLAB; ++i) s += exp2_fast(v[i] - mx);
        al = mx + log2_fast(s);
        #pragma unroll
        for (int i = 0; i < NLAB; ++i) pc[i] = pn[i];
    }
    al += endv[j] * LOG2E;

    // LSE over j (lanes 0..8 hold the distinct values)
    float v[NLAB];
    #pragma unroll
    for (int i = 0; i < NLAB; ++i) v[i] = __shfl(al, i, 64);
    float m01 = fmaxf(v[0], v[1]), m23 = fmaxf(v[2], v[3]);
    float m45 = fmaxf(v[4], v[5]), m67 = fmaxf(v[6], v[7]);
    float mx = fmaxf(fmaxf(fmaxf(m01, m23), fmaxf(m45, m67)), v[8]);
    float s = 0.0f;
    #pragma unroll
    for (int i = 0; i < NLAB; ++i) s += exp2_fast(v[i] - mx);
    float norm = mx + log2_fast(s);

    if (lane == 0) {
        int li = (msum > 0) ? (msum - 1) : 0;
        float score = gsum + startv[lb[0]] * LOG2E + endv[lb[li]] * LOG2E;
        partial[b] = norm - score;
    }
}

// ---------------------------------------------------------------------------
// K4: mean over batches, back to natural-log domain.
// ---------------------------------------------------------------------------
__global__ __launch_bounds__(64) void mean_kernel(
    const float* __restrict__ partial, float* __restrict__ out)
{
    float v = partial[threadIdx.x];
    #pragma unroll
    for (int off = 32; off > 0; off >>= 1) v += __shfl_xor(v, off, 64);
    if (threadIdx.x == 0) out[0] = v * (LN2 / (float)BATCH);
}

extern "C" void kernel_launch(void* const* d_in, const int* in_sizes, int n_in,
                              void* d_out, int out_size, void* d_ws, size_t ws_size,
                              hipStream_t stream)
{
    const float* inp    = (const float*)d_in[0];
    const int*   labels = (const int*)d_in[1];
    const int*   mask   = (const int*)d_in[2];
    const float* W      = (const float*)d_in[3];
    const float* bias   = (const float*)d_in[4];
    const float* trans  = (const float*)d_in[5];
    const float* startv = (const float*)d_in[6];
    const float* endv   = (const float*)d_in[7];

    float* feats   = (float*)d_ws;                    // B*S*L = 294912 floats
    float* P       = feats + BATCH * SEQ * NLAB;      // B*NCHUNK*81 = 82944 floats
    float* partial = P + BATCH * NCHUNK * 81;         // 64 floats
    float* out = (float*)d_out;

    hipLaunchKernelGGL(logits_kernel, dim3(BATCH * SEQ / 8), dim3(256), 0, stream,
                       inp, W, bias, feats);
    hipLaunchKernelGGL(chunk_kernel, dim3((NREC + 6) / 7), dim3(64), 0, stream,
                       feats, trans, mask, P);
    hipLaunchKernelGGL(final_kernel, dim3(BATCH), dim3(64), 0, stream,
                       feats, trans, startv, endv, labels, mask, P, partial);
    hipLaunchKernelGGL(mean_kernel, dim3(1), dim3(64), 0, stream, partial, out);
}

// Round 2
// 235.223 us; speedup vs baseline: 1.0481x; 1.0481x over previous
//
#include <hip/hip_runtime.h>

// CRF sequence labeling: B=64, S=512, H=1024, L=9
// Pipeline:
//   K1 logits_kernel : feats[b][s][l] = (inputs[b,s,:]·W[l,:] + bias[l]) * log2(e)
//                      R2: 16-lane row-groups (4 rows/wave, 64 cols/lane) —
//                      4-level shuffle reduce instead of 6-level, 16 rows/block.
//   K2 chunk_kernel  : per (b, chunk of 32 steps, row i): 9x9 log2-semiring
//                      chunk transfer-matrix row via vector recursion
//   K3 final_kernel  : per batch: alpha0 ⊗ P_0 ⊗ ... ⊗ P_15, + gold path score
//   K4 mean_kernel   : mean over batches * ln(2)
// All log-sum-exp math is done in base-2 domain (inputs pre-scaled by log2 e)
// so LSE = max + log2(sum 2^x) uses raw v_exp_f32/v_log_f32.

#define BATCH 64
#define SEQ   512
#define HID   1024
#define NLAB  9
#define CHUNK 32
#define NCHUNK (SEQ / CHUNK)   // 16
#define NREC (BATCH * NCHUNK * NLAB)  // 9216 row recursions

__device__ __forceinline__ float exp2_fast(float x) { return __builtin_amdgcn_exp2f(x); }
__device__ __forceinline__ float log2_fast(float x) { return __builtin_amdgcn_logf(x); }

#define LOG2E 1.4426950408889634f
#define LN2   0.6931471805599453f

// ---------------------------------------------------------------------------
// K1: logits. Grid: (B*S/16) blocks x 256. Wave handles 4 rows; each row is
// computed by a 16-lane group, each lane covering 4 chunks of 16 contiguous
// cols (coalesced float4 global loads; 16 lanes cover 256 consecutive floats).
// W staged in LDS with +1-per-32-floats skew: phys = col + (col>>5). col0 is
// 16-aligned so the skew term is constant over a lane's 16 cols -> contiguous
// ds_read_b128, ~2-way bank alias (free per m136).
// ---------------------------------------------------------------------------
__global__ __launch_bounds__(256) void logits_kernel(
    const float* __restrict__ inp, const float* __restrict__ Wg,
    const float* __restrict__ bias, float* __restrict__ feats)
{
    __shared__ float Wl[NLAB * 1056];   // 1024 + 32 skew pad per label row
    const int tid = threadIdx.x;
    for (int i = tid; i < NLAB * HID; i += 256) {
        int l = i >> 10, col = i & 1023;
        Wl[l * 1056 + col + (col >> 5)] = Wg[i];
    }
    __syncthreads();

    const int lane = tid & 63;
    const int wv   = tid >> 6;
    const int p    = lane & 15;      // position within 16-lane row group
    const int q    = lane >> 4;      // which of the wave's 4 rows
    const long row = (long)blockIdx.x * 16 + wv * 4 + q;

    const float* r = inp + row * HID;
    float acc[NLAB];
    #pragma unroll
    for (int l = 0; l < NLAB; ++l) acc[l] = 0.f;

    #pragma unroll
    for (int c = 0; c < 4; ++c) {
        const int col0 = c * 256 + p * 16;
        float xs[16];
        #pragma unroll
        for (int qq = 0; qq < 4; ++qq)
            ((float4*)xs)[qq] = ((const float4*)(r + col0))[qq];
        const int sk = col0 + (col0 >> 5);
        #pragma unroll
        for (int l = 0; l < NLAB; ++l) {
            const float* w = &Wl[l * 1056 + sk];
            float a = acc[l];
            #pragma unroll
            for (int k = 0; k < 16; ++k) a = fmaf(xs[k], w[k], a);
            acc[l] = a;
        }
    }

    // reduce across the 16-lane group (4 levels instead of 6)
    #pragma unroll
    for (int l = 0; l < NLAB; ++l) {
        float a = acc[l];
        a += __shfl_xor(a, 8, 64);
        a += __shfl_xor(a, 4, 64);
        a += __shfl_xor(a, 2, 64);
        a += __shfl_xor(a, 1, 64);
        acc[l] = a;
    }
    if (p == 0) {
        float* o = feats + row * NLAB;
        #pragma unroll
        for (int l = 0; l < NLAB; ++l)
            o[l] = (acc[l] + bias[l]) * LOG2E;
    }
}

// ---------------------------------------------------------------------------
// K2: chunk transfer-matrix rows. Each 9-lane group runs one row recursion:
//   row i of P_c = e_i ⊗ M_ts ⊗ ... ⊗ M_{te-1},  M_t[i][j] = trK[i][j]+emitK[t][j]
// Masked steps contribute the identity (0 diag / -1e30 off-diag).
// 7 groups per wave (63 lanes active). Grid: ceil(9216/7) = 1317 blocks x 64.
// ---------------------------------------------------------------------------
__global__ __launch_bounds__(64) void chunk_kernel(
    const float* __restrict__ feats, const float* __restrict__ trans,
    const int* __restrict__ mask, float* __restrict__ P)
{
    const int lane = threadIdx.x;
    const int g = lane / 9;
    const int j = lane - g * 9;
    int rid = blockIdx.x * 7 + g;
    bool act = (g < 7) && (rid < NREC);
    if (!act) rid = 0;

    const int i  = rid % NLAB;
    const int bc = rid / NLAB;
    const int c  = bc & (NCHUNK - 1);
    const int b  = bc >> 4;

    float tr[NLAB];
    #pragma unroll
    for (int k = 0; k < NLAB; ++k) tr[k] = trans[k * NLAB + j] * LOG2E;
    const float tri = trans[i * NLAB + j] * LOG2E;  // direct load, no dyn reg index

    const float* fb = feats + (long)b * SEQ * NLAB;
    const int* mb = mask + b * SEQ;
    const int ts = (c == 0) ? 1 : c * CHUNK;
    const int te = (c + 1) * CHUNK;
    const int sbase = g * 9;

    float a;
    {
        int m0 = mb[ts];
        float e0 = fb[ts * NLAB + j];
        float aid = (i == j) ? 0.0f : -1e30f;
        a = (m0 > 0) ? (tri + e0) : aid;
    }

    float e_nxt = fb[(ts + 1) * NLAB + j];
    int   m_nxt = mb[ts + 1];
    for (int t = ts + 1; t < te; ++t) {
        float e = e_nxt;
        int  mt = m_nxt;
        if (t + 1 < te) {               // prefetch next step's emission/mask
            e_nxt = fb[(t + 1) * NLAB + j];
            m_nxt = mb[t + 1];
        }
        float v[NLAB];
        #pragma unroll
        for (int k = 0; k < NLAB; ++k) v[k] = __shfl(a, sbase + k, 64) + tr[k];
        float m01 = fmaxf(v[0], v[1]), m23 = fmaxf(v[2], v[3]);
        float m45 = fmaxf(v[4], v[5]), m67 = fmaxf(v[6], v[7]);
        float mx = fmaxf(fmaxf(fmaxf(m01, m23), fmaxf(m45, m67)), v[8]);
        float s = 0.0f;
        #pragma unroll
        for (int k = 0; k < NLAB; ++k) s += exp2_fast(v[k] - mx);
        float an = mx + log2_fast(s) + e;
        a = (mt > 0) ? an : a;
    }
    if (act) P[(long)rid * NLAB + j] = a;
}

// ---------------------------------------------------------------------------
// K3: per-batch finalize. Grid: 64 blocks x 64.
//  - gold path score (all 64 lanes, strided over t, then wave-reduce)
//  - alpha = alpha0 ⊗ P_0 ⊗ ... ⊗ P_15 (lanes replicate j = lane%9)
//  - partial[b] = K*(norm - score)
// ---------------------------------------------------------------------------
__global__ __launch_bounds__(64) void final_kernel(
    const float* __restrict__ feats, const float* __restrict__ trans,
    const float* __restrict__ startv, const float* __restrict__ endv,
    const int* __restrict__ labels, const int* __restrict__ mask,
    const float* __restrict__ P, float* __restrict__ partial)
{
    const int b = blockIdx.x, lane = threadIdx.x;
    const float* fb = feats + (long)b * SEQ * NLAB;
    const int* lb = labels + b * SEQ;
    const int* mb = mask + b * SEQ;

    // ---- gold score ----
    float gsum = 0.0f; int msum = 0;
    for (int t = lane; t < SEQ; t += 64) {
        int tag = lb[t];
        int mt = mb[t];
        if (mt > 0) {
            gsum += fb[t * NLAB + tag];            // feats already *K
            msum++;
            if (t > 0) gsum += trans[lb[t - 1] * NLAB + tag] * LOG2E;
        }
    }
    #pragma unroll
    for (int off = 32; off > 0; off >>= 1) {
        gsum += __shfl_xor(gsum, off, 64);
        msum += __shfl_xor(msum, off, 64);
    }

    // ---- alpha chain over chunk matrices ----
    const int j = lane % 9;      // lanes >=9 replicate; shuffles read lanes 0..8
    float al = fb[j] + startv[j] * LOG2E;
    const float* Pb = P + (long)b * NCHUNK * 81;
    float pc[NLAB];
    #pragma unroll
    for (int i = 0; i < NLAB; ++i) pc[i] = Pb[i * NLAB + j];
    #pragma unroll
    for (int c = 0; c < NCHUNK; ++c) {
        float pn[NLAB];
        if (c < NCHUNK - 1) {
            #pragma unroll
            for (int i = 0; i < NLAB; ++i) pn[i] = Pb[(c + 1) * 81 + i * NLAB + j];
        } else {
            #pragma unroll
            for (int i = 0; i < NLAB; ++i) pn[i] = 0.0f;
        }
        float v[NLAB];
        #pragma unroll
        for (int i = 0; i < NLAB; ++i) v[i] = __shfl(al, i, 64) + pc[i];
        float m01 = fmaxf(v[0], v[1]), m23 = fmaxf(v[2], v[3]);
        float m45 = fmaxf(v[4], v[5]), m67 = fmaxf(v[6], v[7]);
        float mx = fmaxf(fmaxf(fmaxf(m01, m23), fmaxf(m45, m67)), v[8]);
        float s = 0.0f;
        #pragma unroll
        for (int i = 0; i < NLAB; ++i) s += exp2_fast(v[i] - mx);
        al = mx + log2_fast(s);
        #pragma unroll
        for (int i = 0; i < NLAB; ++i) pc[i] = pn[i];
    }
    al += endv[j] * LOG2E;

    // LSE over j (lanes 0..8 hold the distinct values)
    float v[NLAB];
    #pragma unroll
    for (int i = 0; i < NLAB; ++i) v[i] = __shfl(al, i, 64);
    float m01 = fmaxf(v[0], v[1]), m23 = fmaxf(v[2], v[3]);
    float m45 = fmaxf(v[4], v[5]), m67 = fmaxf(v[6], v[7]);
    float mx = fmaxf(fmaxf(fmaxf(m01, m23), fmaxf(m45, m67)), v[8]);
    float s = 0.0f;
    #pragma unroll
    for (int i = 0; i < NLAB; ++i) s += exp2_fast(v[i] - mx);
    float norm = mx + log2_fast(s);

    if (lane == 0) {
        int li = (msum > 0) ? (msum - 1) : 0;
        float score = gsum + startv[lb[0]] * LOG2E + endv[lb[li]] * LOG2E;
        partial[b] = norm - score;
    }
}

// ---------------------------------------------------------------------------
// K4: mean over batches, back to natural-log domain.
// ---------------------------------------------------------------------------
__global__ __launch_bounds__(64) void mean_kernel(
    const float* __restrict__ partial, float* __restrict__ out)
{
    float v = partial[threadIdx.x];
    #pragma unroll
    for (int off = 32; off > 0; off >>= 1) v += __shfl_xor(v, off, 64);
    if (threadIdx.x == 0) out[0] = v * (LN2 / (float)BATCH);
}

extern "C" void kernel_launch(void* const* d_in, const int* in_sizes, int n_in,
                              void* d_out, int out_size, void* d_ws, size_t ws_size,
                              hipStream_t stream)
{
    const float* inp    = (const float*)d_in[0];
    const int*   labels = (const int*)d_in[1];
    const int*   mask   = (const int*)d_in[2];
    const float* W      = (const float*)d_in[3];
    const float* bias   = (const float*)d_in[4];
    const float* trans  = (const float*)d_in[5];
    const float* startv = (const float*)d_in[6];
    const float* endv   = (const float*)d_in[7];

    float* feats   = (float*)d_ws;                    // B*S*L = 294912 floats
    float* P       = feats + BATCH * SEQ * NLAB;      // B*NCHUNK*81 = 82944 floats
    float* partial = P + BATCH * NCHUNK * 81;         // 64 floats
    float* out = (float*)d_out;

    hipLaunchKernelGGL(logits_kernel, dim3(BATCH * SEQ / 16), dim3(256), 0, stream,
                       inp, W, bias, feats);
    hipLaunchKernelGGL(chunk_kernel, dim3((NREC + 6) / 7), dim3(64), 0, stream,
                       feats, trans, mask, P);
    hipLaunchKernelGGL(final_kernel, dim3(BATCH), dim3(64), 0, stream,
                       feats, trans, startv, endv, labels, mask, P, partial);
    hipLaunchKernelGGL(mean_kernel, dim3(1), dim3(64), 0, stream, partial, out);
}